// Round 12
// baseline (536.875 us; speedup 1.0000x reference)
//
#include <hip/hip_runtime.h>
#include <math.h>

// Problem constants
#define NPTS   131072          // 32*64*64 points
#define DIMS   64              // embedding dim / channels
#define KCODES 512             // codebook size
#define HW     4096            // 64*64 spatial

// d_out flat offsets (floats), reference tuple order:
// (loss, quantized_out[NCHW], perplexity, encodings, quantized_flat)
#define OFF_LOSS 0
#define OFF_QOUT 1
#define OFF_PERP 8388609
#define OFF_ENC  8388610
#define OFF_QF   75497474   // 8388610 + 67108864

// d_ws byte offsets (R3 layout)
#define WS_HIST  0          // unsigned[512]  (zeroed by vq_prep)
#define WS_BLOSS 2048       // float[2048]
#define WS_NRM   10240      // float[512]
#define WS_EH    12288      // ushort[512*64] bf16 hi, MFMA-fragment order
#define WS_EL    77824      // ushort[512*64] bf16 lo, MFMA-fragment order

// split-bf16 distance error <~2.4e-4; pairwise comparison error <4.8e-4.
// margin 2e-3 still flags every possible argmin flip (4x cushion).
#define EPS_MARGIN 2e-3f

#define NBLK   512             // persistent blocks (2/CU)
#define NTILE  2048            // 64-point tiles
#define TPB    (NTILE / NBLK)  // 4 tiles per block

typedef __attribute__((ext_vector_type(8))) short short8;
typedef __attribute__((ext_vector_type(4))) float f32x4;

__device__ __forceinline__ unsigned short f2bf(float f) {
    unsigned u = __float_as_uint(f);
    unsigned r = (u + 0x7fffu + ((u >> 16) & 1u)) >> 16;   // RNE
    return (unsigned short)r;
}
__device__ __forceinline__ float bf2f(unsigned short h) {
    return __uint_as_float(((unsigned)h) << 16);
}

// ---------------------------------------------------------------------------
// Prep: split codebook into bf16 hi/lo in MFMA B-fragment order (see R3).
// Also zeroes hist.
// ---------------------------------------------------------------------------
__global__ void vq_prep(const float* __restrict__ emb,
                        unsigned short* __restrict__ ehF,
                        unsigned short* __restrict__ elF,
                        float* __restrict__ nrm,
                        unsigned* __restrict__ hist)
{
    int k = blockIdx.x;      // 512
    int d = threadIdx.x;     // 64
    float v = emb[k * DIMS + d];
    unsigned short h = f2bf(v);
    int t = k >> 4, col = k & 15;
    int s = d >> 5, quad = (d >> 3) & 3, j = d & 7;
    int idx = (((t * 2 + s) * 64) + quad * 16 + col) * 8 + j;
    ehF[idx] = h;
    elF[idx] = f2bf(v - bf2f(h));
    double sq = (double)v * (double)v;
    #pragma unroll
    for (int off = 32; off > 0; off >>= 1)
        sq += __shfl_down(sq, off, 64);
    if (d == 0) { nrm[k] = (float)sq; hist[k] = 0u; }
}

// ---------------------------------------------------------------------------
// ROUND-12: PERSISTENT GRID-STRIDE. Evidence: per-block effective cost is
// ~27us INVARIANT to content (8 structural nulls); R5 measured block 0's
// critical path at 14.4us for ~2.5us of work with zero queueing; all pipes
// <15% busy. Model: fixed per-block-lifetime cost (cold I-fetch of the
// multi-KB body at serialized L2 latency + block setup/drain) x 2048
// lifetimes. Fix: amortize — 512 persistent single-wave blocks each
// grid-striding over 4 tiles (R11 body per tile, byte-identical); codebook
// norms staged ONCE per block; I-cache warm after first tile. Per-CU
// lifetimes 8 -> 2.
// ---------------------------------------------------------------------------
__global__ __launch_bounds__(64, 2) void vq_fused(
    const float*          __restrict__ in,    // NCHW [32][64][64][64]
    const float*          __restrict__ emb,   // [512][64] fp32 (recheck+gather)
    const unsigned short* __restrict__ eh,    // frag-order bf16 hi
    const unsigned short* __restrict__ el,    // frag-order bf16 lo
    const float*          __restrict__ nrm,   // [512] ||e||^2 fp32
    unsigned*             __restrict__ hist,  // [512]
    float*                __restrict__ bloss, // [2048]
    float*                __restrict__ out)
{
    __shared__ float xs[64 * 68];   // [p][d] x-tile, stride 68 (17.4 KB); reused as qs
    __shared__ float nsL[512];
    __shared__ float psxL[64];
    __shared__ float pdistL[64];
    __shared__ int   fidxL[64];
    __shared__ int   flaggedL[64];
    __shared__ int   nflag;
    // ~20 KB

    const int lane = threadIdx.x;        // 64

    // ---- stage codebook norms ONCE per block ----
    {
        const float4* nv = (const float4*)nrm;
        float4 a = nv[lane * 2];
        float4 c = nv[lane * 2 + 1];
        *(float4*)&nsL[lane * 8]     = a;
        *(float4*)&nsL[lane * 8 + 4] = c;
    }

    const int col  = lane & 15;
    const int quad = lane >> 4;

    #pragma unroll 1
    for (int tile = blockIdx.x; tile < NTILE; tile += NBLK) {

    const int b    = tile >> 6;
    const int hw0  = (tile & 63) * 64;
    const long inBase = (long)b * (DIMS * HW) + hw0;

    // ---- stage x tile [p][d]: thread lane owns point lane (coalesced per d) ----
    {
        float ps = 0.f;
        #pragma unroll 8
        for (int d = 0; d < 64; d++) {
            float v = in[inBase + (long)d * HW + lane];
            xs[lane * 68 + d] = v;
            ps = fmaf(v, v, ps);
        }
        psxL[lane] = ps;
    }
    if (lane == 0) nflag = 0;
    __syncthreads();

    // ---- A-fragments for ALL 4 point-groups ----
    short8 ah[4][2], al[4][2];
    #pragma unroll
    for (int pg = 0; pg < 4; pg++) {
        const float* xrow = &xs[(pg * 16 + col) * 68];
        #pragma unroll
        for (int s = 0; s < 2; s++) {
            int k0 = s * 32 + quad * 8;
            float xv[8];
            *(float4*)&xv[0] = *(const float4*)&xrow[k0];
            *(float4*)&xv[4] = *(const float4*)&xrow[k0 + 4];
            short8 h, lo;
            #pragma unroll
            for (int j = 0; j < 8; j++) {
                unsigned short hb = f2bf(xv[j]);
                h[j]  = (short)hb;
                lo[j] = (short)f2bf(xv[j] - bf2f(hb));
            }
            ah[pg][s] = h; al[pg][s] = lo;
        }
    }

    float b1[4][4], b2[4][4];
    int   i1[4][4];
    #pragma unroll
    for (int pg = 0; pg < 4; pg++)
        #pragma unroll
        for (int r = 0; r < 4; r++) { b1[pg][r] = 1e30f; b2[pg][r] = 1e30f; i1[pg][r] = 0; }

    // ---- ROLLED t-loop: 512 codes; 4 loads feed 24 MFMAs; manual prefetch ----
    {
        const short8* bhF = (const short8*)eh;   // [t*128 + {0,64} + lane]
        const short8* blF = (const short8*)el;

        short8 bh0 = bhF[lane],      bh1 = bhF[64 + lane];
        short8 bl0 = blF[lane],      bl1 = blF[64 + lane];

        #pragma unroll 1
        for (int t = 0; t < 32; t++) {
            short8 nh0, nh1, nl0, nl1;
            if (t < 31) {                        // uniform branch
                int base = (t + 1) * 128 + lane;
                nh0 = bhF[base];      nh1 = bhF[base + 64];
                nl0 = blF[base];      nl1 = blF[base + 64];
            }

            const int   k  = t * 16 + col;
            const float nk = nsL[k];

            #pragma unroll
            for (int pg = 0; pg < 4; pg++) {
                f32x4 acc = {0.f, 0.f, 0.f, 0.f};
                acc = __builtin_amdgcn_mfma_f32_16x16x32_bf16(ah[pg][0], bh0, acc, 0, 0, 0);
                acc = __builtin_amdgcn_mfma_f32_16x16x32_bf16(ah[pg][1], bh1, acc, 0, 0, 0);
                acc = __builtin_amdgcn_mfma_f32_16x16x32_bf16(ah[pg][0], bl0, acc, 0, 0, 0);
                acc = __builtin_amdgcn_mfma_f32_16x16x32_bf16(ah[pg][1], bl1, acc, 0, 0, 0);
                acc = __builtin_amdgcn_mfma_f32_16x16x32_bf16(al[pg][0], bh0, acc, 0, 0, 0);
                acc = __builtin_amdgcn_mfma_f32_16x16x32_bf16(al[pg][1], bh1, acc, 0, 0, 0);

                #pragma unroll
                for (int r = 0; r < 4; r++) {
                    float v = fmaf(-2.f, acc[r], nk);   // ||e||^2 - 2 x.e
                    bool better = (v < b1[pg][r]);
                    b2[pg][r] = better ? b1[pg][r] : fminf(b2[pg][r], v);
                    i1[pg][r] = better ? k : i1[pg][r];
                    b1[pg][r] = better ? v : b1[pg][r];
                }
            }

            if (t < 31) {
                bh0 = nh0; bh1 = nh1; bl0 = nl0; bl1 = nl1;
            }
        }
    }

    // ---- reduce over 16 code-columns ----
    #pragma unroll
    for (int pg = 0; pg < 4; pg++) {
        #pragma unroll
        for (int r = 0; r < 4; r++) {
            float b1v = b1[pg][r], b2v = b2[pg][r];
            int   i1v = i1[pg][r];
            #pragma unroll
            for (int m = 1; m < 16; m <<= 1) {
                float ob1 = __shfl_xor(b1v, m);
                int   oi1 = __shfl_xor(i1v, m);
                float ob2 = __shfl_xor(b2v, m);
                float loser = fmaxf(b1v, ob1);
                b2v = fminf(fminf(b2v, ob2), loser);
                if (ob1 < b1v || (ob1 == b1v && oi1 < i1v)) { b1v = ob1; i1v = oi1; }
            }
            if (col == 0) {
                int p = pg * 16 + quad * 4 + r;   // D row = quad*4 + reg
                fidxL[p] = i1v;
                pdistL[p] = psxL[p] + b1v;
                if (b2v - b1v < EPS_MARGIN) {
                    int s = atomicAdd(&nflag, 1);
                    flaggedL[s] = p;
                }
            }
        }
    }
    __syncthreads();

    // ---- wave fp64 re-scan for near-tie points (rare) ----
    {
        int nf = nflag;
        for (int f = 0; f < nf; f++) {
            int p = flaggedL[f];
            double bd = 1e300;
            int    bk = 1 << 30;
            #pragma unroll 1
            for (int kk = 0; kk < 8; kk++) {
                int k = (kk << 6) + lane;        // lane's codes: lane, lane+64, ...
                const float4* er = (const float4*)(emb + k * DIMS);
                double s = 0.0;
                #pragma unroll 4
                for (int i = 0; i < 16; i++) {
                    float4 e4 = er[i];
                    double d0 = (double)xs[p * 68 + i * 4    ] - (double)e4.x;
                    double d1 = (double)xs[p * 68 + i * 4 + 1] - (double)e4.y;
                    double d2 = (double)xs[p * 68 + i * 4 + 2] - (double)e4.z;
                    double d3 = (double)xs[p * 68 + i * 4 + 3] - (double)e4.w;
                    s = fma(d0, d0, s); s = fma(d1, d1, s);
                    s = fma(d2, d2, s); s = fma(d3, d3, s);
                }
                if (s < bd || (s == bd && k < bk)) { bd = s; bk = k; }
            }
            #pragma unroll
            for (int off = 32; off > 0; off >>= 1) {
                double ov = __shfl_down(bd, off);
                int    ok = __shfl_down(bk, off);
                if (ov < bd || (ov == bd && ok < bk)) { bd = ov; bk = ok; }
            }
            if (lane == 0) {
                fidxL[p]  = bk;
                pdistL[p] = (float)bd;
            }
        }
    }
    __syncthreads();   // fidx/pdist final before hist + stores

    // ---- histogram + loss partial ----
    {
        atomicAdd(&hist[fidxL[lane]], 1u);
        float lp = pdistL[lane];
        #pragma unroll
        for (int off = 32; off > 0; off >>= 1)
            lp += __shfl_down(lp, off);
        if (lane == 0) bloss[tile] = lp;
    }
    __syncthreads();   // all xs reads done before qs overwrite

    // ---- stage chosen embedding rows into qs (aliases xs, stride 65) ----
    float* qs = xs;
    {
        #pragma unroll 1
        for (int g = 0; g < 4; g++) {
            int vt = g * 64 + lane;
            int q = vt & 3, p = vt >> 2;
            int row = fidxL[p];
            const float4* src = (const float4*)(emb + row * DIMS + q * 16);
            #pragma unroll
            for (int i = 0; i < 4; i++) {
                float4 v = src[i];
                int base = p * 65 + q * 16 + i * 4;
                qs[base] = v.x; qs[base + 1] = v.y; qs[base + 2] = v.z; qs[base + 3] = v.w;
            }
        }
    }

    const int n0 = b * HW + hw0;

    // ---- encodings: 64 one-hot rows (rolled store loop) ----
    {
        float* encB = out + (long)OFF_ENC + (long)n0 * KCODES;
        #pragma unroll 1
        for (int i = 0; i < 128; i++) {
            int f  = i * 256 + lane * 4;     // 32768 floats
            int p  = f >> 9;
            int k0 = f & 511;
            int fd = fidxL[p];
            f32x4 v;
            v.x = (k0     == fd) ? 1.0f : 0.0f;
            v.y = (k0 + 1 == fd) ? 1.0f : 0.0f;
            v.z = (k0 + 2 == fd) ? 1.0f : 0.0f;
            v.w = (k0 + 3 == fd) ? 1.0f : 0.0f;
            __builtin_nontemporal_store(v, (f32x4*)(encB + f));
        }
    }
    __syncthreads();   // qs staged before transpose reads

    // ---- quantized_flat [n][64] (rolled) ----
    {
        float* qfB = out + (long)OFF_QF + (long)n0 * DIMS;
        #pragma unroll 1
        for (int i = 0; i < 16; i++) {
            int f = i * 256 + lane * 4;      // 4096 floats
            int p = f >> 6;
            int d = f & 63;
            f32x4 v;
            v.x = qs[p * 65 + d];     v.y = qs[p * 65 + d + 1];
            v.z = qs[p * 65 + d + 2]; v.w = qs[p * 65 + d + 3];
            __builtin_nontemporal_store(v, (f32x4*)(qfB + f));
        }
    }

    // ---- quantized_out NCHW: 1024 float4 per tile (rolled) ----
    {
        float* qoB = out + (long)OFF_QOUT + (long)b * (DIMS * HW) + hw0;
        #pragma unroll 1
        for (int i = 0; i < 16; i++) {
            int f4  = i * 64 + lane;         // 1024 float4
            int d   = f4 >> 4;               // row 0..63
            int seg = f4 & 15;               // float4 segment within row
            f32x4 v;
            v.x = qs[(seg * 4    ) * 65 + d];
            v.y = qs[(seg * 4 + 1) * 65 + d];
            v.z = qs[(seg * 4 + 2) * 65 + d];
            v.w = qs[(seg * 4 + 3) * 65 + d];
            __builtin_nontemporal_store(v, (f32x4*)(qoB + (long)d * HW + seg * 4));
        }
    }
    __syncthreads();   // qs (=xs) free before next tile's staging

    }   // tile loop
}

// ---------------------------------------------------------------------------
// Finalize: loss scalar + perplexity (fp64)
// ---------------------------------------------------------------------------
__global__ void vq_finalize(const unsigned* __restrict__ hist,
                            const float* __restrict__ bloss,
                            float* __restrict__ out)
{
    __shared__ double sl[512];
    __shared__ double sh[512];
    int tid = threadIdx.x;   // 512

    double l = (double)bloss[tid] + (double)bloss[tid + 512]
             + (double)bloss[tid + 1024] + (double)bloss[tid + 1536];

    unsigned c = hist[tid];
    double p = (double)c * (1.0 / 131072.0);
    double h = p * log(p + 1e-10);

    sl[tid] = l;
    sh[tid] = h;
    __syncthreads();
    for (int s = 256; s > 0; s >>= 1) {
        if (tid < s) { sl[tid] += sl[tid + s]; sh[tid] += sh[tid + s]; }
        __syncthreads();
    }
    if (tid == 0) {
        out[OFF_LOSS] = (float)(0.25 * sl[0] / 8388608.0);
        out[OFF_PERP] = (float)exp(-sh[0]);
    }
}

// ---------------------------------------------------------------------------
extern "C" void kernel_launch(void* const* d_in, const int* in_sizes, int n_in,
                              void* d_out, int out_size, void* d_ws, size_t ws_size,
                              hipStream_t stream)
{
    const float* in  = (const float*)d_in[0];   // inputs  [32,64,64,64] f32
    const float* emb = (const float*)d_in[1];   // codebook [512,64] f32
    float* out = (float*)d_out;
    char*  ws  = (char*)d_ws;

    unsigned*       hist  = (unsigned*)      (ws + WS_HIST);
    float*          bloss = (float*)         (ws + WS_BLOSS);
    float*          nrm   = (float*)         (ws + WS_NRM);
    unsigned short* eh    = (unsigned short*)(ws + WS_EH);
    unsigned short* el    = (unsigned short*)(ws + WS_EL);

    vq_prep<<<KCODES, 64, 0, stream>>>(emb, eh, el, nrm, hist);
    vq_fused<<<NBLK, 64, 0, stream>>>(in, emb, eh, el, nrm, hist, bloss, out);
    vq_finalize<<<1, 512, 0, stream>>>(hist, bloss, out);
}

// Round 13
// 521.488 us; speedup vs baseline: 1.0295x; 1.0295x over previous
//
#include <hip/hip_runtime.h>
#include <math.h>

// Problem constants
#define NPTS   131072          // 32*64*64 points
#define DIMS   64              // embedding dim / channels
#define KCODES 512             // codebook size
#define HW     4096            // 64*64 spatial

// d_out flat offsets (floats), reference tuple order:
// (loss, quantized_out[NCHW], perplexity, encodings, quantized_flat)
#define OFF_LOSS 0
#define OFF_QOUT 1
#define OFF_PERP 8388609
#define OFF_ENC  8388610
#define OFF_QF   75497474   // 8388610 + 67108864

// d_ws byte offsets (R3 layout)
#define WS_HIST  0          // unsigned[512]  (zeroed by vq_prep)
#define WS_BLOSS 2048       // float[2048]
#define WS_NRM   10240      // float[512]
#define WS_EH    12288      // ushort[512*64] bf16 hi, MFMA-fragment order
#define WS_EL    77824      // ushort[512*64] bf16 lo, MFMA-fragment order

// split-bf16 distance error <~2.4e-4; pairwise comparison error <4.8e-4.
// margin 2e-3 still flags every possible argmin flip (4x cushion).
#define EPS_MARGIN 2e-3f

typedef __attribute__((ext_vector_type(8))) short short8;
typedef __attribute__((ext_vector_type(4))) float f32x4;

__device__ __forceinline__ unsigned short f2bf(float f) {
    unsigned u = __float_as_uint(f);
    unsigned r = (u + 0x7fffu + ((u >> 16) & 1u)) >> 16;   // RNE
    return (unsigned short)r;
}
__device__ __forceinline__ float bf2f(unsigned short h) {
    return __uint_as_float(((unsigned)h) << 16);
}

// ---------------------------------------------------------------------------
// Prep: split codebook into bf16 hi/lo in MFMA B-fragment order (see R3).
// Also zeroes hist.
// ---------------------------------------------------------------------------
__global__ void vq_prep(const float* __restrict__ emb,
                        unsigned short* __restrict__ ehF,
                        unsigned short* __restrict__ elF,
                        float* __restrict__ nrm,
                        unsigned* __restrict__ hist)
{
    int k = blockIdx.x;      // 512
    int d = threadIdx.x;     // 64
    float v = emb[k * DIMS + d];
    unsigned short h = f2bf(v);
    int t = k >> 4, col = k & 15;
    int s = d >> 5, quad = (d >> 3) & 3, j = d & 7;
    int idx = (((t * 2 + s) * 64) + quad * 16 + col) * 8 + j;
    ehF[idx] = h;
    elF[idx] = f2bf(v - bf2f(h));
    double sq = (double)v * (double)v;
    #pragma unroll
    for (int off = 32; off > 0; off >>= 1)
        sq += __shfl_down(sq, off, 64);
    if (d == 0) { nrm[k] = (float)sq; hist[k] = 0u; }
}

// ---------------------------------------------------------------------------
// ROUND-13: WRITE-STREAM THEORY. Per-CU tile throughput is ~25-33us across 9
// structural variants; hbm_gbps stuck at 1.4-1.7 TB/s (25% of fill's 6.3);
// all pipes idle. Model: 512-1536 concurrent write streams 128KB apart (enc)
// + 256B page-scattered qout => DRAM row thrash caps effective write BW.
// Split: scan keeps compute + qf + qout + stashes fidx at enc row starts;
// vq_enc rewrites enc (268MB, 80% of traffic) FILL-STYLE: 524288 lanes x
// 16B/iter grid-stride = one contiguous 8MB window sweeping linearly
// (fillBuffer's exact pattern, which hits 6.3 TB/s). Lanes skip each row's
// first f4 (the stash); vq_fix rewrites those last.
// ---------------------------------------------------------------------------
__global__ __launch_bounds__(64, 2) void vq_scan(
    const float*          __restrict__ in,    // NCHW [32][64][64][64]
    const float*          __restrict__ emb,   // [512][64] fp32 (recheck+gather)
    const unsigned short* __restrict__ eh,    // frag-order bf16 hi
    const unsigned short* __restrict__ el,    // frag-order bf16 lo
    const float*          __restrict__ nrm,   // [512] ||e||^2 fp32
    unsigned*             __restrict__ hist,  // [512]
    float*                __restrict__ bloss, // [2048]
    float*                __restrict__ out)
{
    __shared__ float xs[64 * 68];   // [p][d] x-tile, stride 68 (17.4 KB); reused as qs
    __shared__ float nsL[512];
    __shared__ float psxL[64];
    __shared__ float pdistL[64];
    __shared__ int   fidxL[64];
    __shared__ int   flaggedL[64];
    __shared__ int   nflag;

    const int lane = threadIdx.x;        // 64
    const int blk  = blockIdx.x;         // 2048 tiles of 64 points
    const int b    = blk >> 6;
    const int hw0  = (blk & 63) * 64;
    const long inBase = (long)b * (DIMS * HW) + hw0;

    // ---- stage x tile [p][d] ----
    {
        float ps = 0.f;
        #pragma unroll 8
        for (int d = 0; d < 64; d++) {
            float v = in[inBase + (long)d * HW + lane];
            xs[lane * 68 + d] = v;
            ps = fmaf(v, v, ps);
        }
        psxL[lane] = ps;
    }
    // ---- stage codebook norms ----
    {
        const float4* nv = (const float4*)nrm;
        float4 a = nv[lane * 2];
        float4 c = nv[lane * 2 + 1];
        *(float4*)&nsL[lane * 8]     = a;
        *(float4*)&nsL[lane * 8 + 4] = c;
    }
    if (lane == 0) nflag = 0;
    __syncthreads();

    const int col  = lane & 15;
    const int quad = lane >> 4;

    // ---- A-fragments for ALL 4 point-groups ----
    short8 ah[4][2], al[4][2];
    #pragma unroll
    for (int pg = 0; pg < 4; pg++) {
        const float* xrow = &xs[(pg * 16 + col) * 68];
        #pragma unroll
        for (int s = 0; s < 2; s++) {
            int k0 = s * 32 + quad * 8;
            float xv[8];
            *(float4*)&xv[0] = *(const float4*)&xrow[k0];
            *(float4*)&xv[4] = *(const float4*)&xrow[k0 + 4];
            short8 h, lo;
            #pragma unroll
            for (int j = 0; j < 8; j++) {
                unsigned short hb = f2bf(xv[j]);
                h[j]  = (short)hb;
                lo[j] = (short)f2bf(xv[j] - bf2f(hb));
            }
            ah[pg][s] = h; al[pg][s] = lo;
        }
    }

    float b1[4][4], b2[4][4];
    int   i1[4][4];
    #pragma unroll
    for (int pg = 0; pg < 4; pg++)
        #pragma unroll
        for (int r = 0; r < 4; r++) { b1[pg][r] = 1e30f; b2[pg][r] = 1e30f; i1[pg][r] = 0; }

    // ---- ROLLED t-loop: 512 codes; 4 loads feed 24 MFMAs; manual prefetch ----
    {
        const short8* bhF = (const short8*)eh;   // [t*128 + {0,64} + lane]
        const short8* blF = (const short8*)el;

        short8 bh0 = bhF[lane],      bh1 = bhF[64 + lane];
        short8 bl0 = blF[lane],      bl1 = blF[64 + lane];

        #pragma unroll 1
        for (int t = 0; t < 32; t++) {
            short8 nh0, nh1, nl0, nl1;
            if (t < 31) {                        // uniform branch
                int base = (t + 1) * 128 + lane;
                nh0 = bhF[base];      nh1 = bhF[base + 64];
                nl0 = blF[base];      nl1 = blF[base + 64];
            }

            const int   k  = t * 16 + col;
            const float nk = nsL[k];

            #pragma unroll
            for (int pg = 0; pg < 4; pg++) {
                f32x4 acc = {0.f, 0.f, 0.f, 0.f};
                acc = __builtin_amdgcn_mfma_f32_16x16x32_bf16(ah[pg][0], bh0, acc, 0, 0, 0);
                acc = __builtin_amdgcn_mfma_f32_16x16x32_bf16(ah[pg][1], bh1, acc, 0, 0, 0);
                acc = __builtin_amdgcn_mfma_f32_16x16x32_bf16(ah[pg][0], bl0, acc, 0, 0, 0);
                acc = __builtin_amdgcn_mfma_f32_16x16x32_bf16(ah[pg][1], bl1, acc, 0, 0, 0);
                acc = __builtin_amdgcn_mfma_f32_16x16x32_bf16(al[pg][0], bh0, acc, 0, 0, 0);
                acc = __builtin_amdgcn_mfma_f32_16x16x32_bf16(al[pg][1], bh1, acc, 0, 0, 0);

                #pragma unroll
                for (int r = 0; r < 4; r++) {
                    float v = fmaf(-2.f, acc[r], nk);   // ||e||^2 - 2 x.e
                    bool better = (v < b1[pg][r]);
                    b2[pg][r] = better ? b1[pg][r] : fminf(b2[pg][r], v);
                    i1[pg][r] = better ? k : i1[pg][r];
                    b1[pg][r] = better ? v : b1[pg][r];
                }
            }

            if (t < 31) {
                bh0 = nh0; bh1 = nh1; bl0 = nl0; bl1 = nl1;
            }
        }
    }

    // ---- reduce over 16 code-columns ----
    #pragma unroll
    for (int pg = 0; pg < 4; pg++) {
        #pragma unroll
        for (int r = 0; r < 4; r++) {
            float b1v = b1[pg][r], b2v = b2[pg][r];
            int   i1v = i1[pg][r];
            #pragma unroll
            for (int m = 1; m < 16; m <<= 1) {
                float ob1 = __shfl_xor(b1v, m);
                int   oi1 = __shfl_xor(i1v, m);
                float ob2 = __shfl_xor(b2v, m);
                float loser = fmaxf(b1v, ob1);
                b2v = fminf(fminf(b2v, ob2), loser);
                if (ob1 < b1v || (ob1 == b1v && oi1 < i1v)) { b1v = ob1; i1v = oi1; }
            }
            if (col == 0) {
                int p = pg * 16 + quad * 4 + r;   // D row = quad*4 + reg
                fidxL[p] = i1v;
                pdistL[p] = psxL[p] + b1v;
                if (b2v - b1v < EPS_MARGIN) {
                    int s = atomicAdd(&nflag, 1);
                    flaggedL[s] = p;
                }
            }
        }
    }
    __syncthreads();

    // ---- wave fp64 re-scan for near-tie points (rare) ----
    {
        int nf = nflag;
        for (int f = 0; f < nf; f++) {
            int p = flaggedL[f];
            double bd = 1e300;
            int    bk = 1 << 30;
            #pragma unroll 1
            for (int kk = 0; kk < 8; kk++) {
                int k = (kk << 6) + lane;        // lane's codes: lane, lane+64, ...
                const float4* er = (const float4*)(emb + k * DIMS);
                double s = 0.0;
                #pragma unroll 4
                for (int i = 0; i < 16; i++) {
                    float4 e4 = er[i];
                    double d0 = (double)xs[p * 68 + i * 4    ] - (double)e4.x;
                    double d1 = (double)xs[p * 68 + i * 4 + 1] - (double)e4.y;
                    double d2 = (double)xs[p * 68 + i * 4 + 2] - (double)e4.z;
                    double d3 = (double)xs[p * 68 + i * 4 + 3] - (double)e4.w;
                    s = fma(d0, d0, s); s = fma(d1, d1, s);
                    s = fma(d2, d2, s); s = fma(d3, d3, s);
                }
                if (s < bd || (s == bd && k < bk)) { bd = s; bk = k; }
            }
            #pragma unroll
            for (int off = 32; off > 0; off >>= 1) {
                double ov = __shfl_down(bd, off);
                int    ok = __shfl_down(bk, off);
                if (ov < bd || (ov == bd && ok < bk)) { bd = ov; bk = ok; }
            }
            if (lane == 0) {
                fidxL[p]  = bk;
                pdistL[p] = (float)bd;
            }
        }
    }
    __syncthreads();   // fidx/pdist final before hist + stores

    const int n0 = b * HW + hw0;

    // ---- histogram + loss partial + fidx stash at enc row starts ----
    {
        atomicAdd(&hist[fidxL[lane]], 1u);
        // stash (raw int bits) at first float of point's enc row; vq_enc
        // reads it (and skips writing that f4); vq_fix rewrites it last.
        *(int*)(out + (long)OFF_ENC + ((long)(n0 + lane)) * KCODES) = fidxL[lane];
        float lp = pdistL[lane];
        #pragma unroll
        for (int off = 32; off > 0; off >>= 1)
            lp += __shfl_down(lp, off);
        if (lane == 0) bloss[blk] = lp;
    }
    __syncthreads();   // all xs reads done before qs overwrite

    // ---- stage chosen embedding rows into qs (aliases xs, stride 65) ----
    float* qs = xs;
    {
        #pragma unroll 1
        for (int g = 0; g < 4; g++) {
            int vt = g * 64 + lane;
            int q = vt & 3, p = vt >> 2;
            int row = fidxL[p];
            const float4* src = (const float4*)(emb + row * DIMS + q * 16);
            #pragma unroll
            for (int i = 0; i < 4; i++) {
                float4 v = src[i];
                int base = p * 65 + q * 16 + i * 4;
                qs[base] = v.x; qs[base + 1] = v.y; qs[base + 2] = v.z; qs[base + 3] = v.w;
            }
        }
    }
    __syncthreads();   // qs staged before transpose reads

    // ---- quantized_flat [n][64] (rolled) ----
    {
        float* qfB = out + (long)OFF_QF + (long)n0 * DIMS;
        #pragma unroll 1
        for (int i = 0; i < 16; i++) {
            int f = i * 256 + lane * 4;      // 4096 floats
            int p = f >> 6;
            int d = f & 63;
            f32x4 v;
            v.x = qs[p * 65 + d];     v.y = qs[p * 65 + d + 1];
            v.z = qs[p * 65 + d + 2]; v.w = qs[p * 65 + d + 3];
            __builtin_nontemporal_store(v, (f32x4*)(qfB + f));
        }
    }

    // ---- quantized_out NCHW: 1024 float4 per tile (rolled) ----
    {
        float* qoB = out + (long)OFF_QOUT + (long)b * (DIMS * HW) + hw0;
        #pragma unroll 1
        for (int i = 0; i < 16; i++) {
            int f4  = i * 64 + lane;         // 1024 float4
            int d   = f4 >> 4;               // row 0..63
            int seg = f4 & 15;               // float4 segment within row
            f32x4 v;
            v.x = qs[(seg * 4    ) * 65 + d];
            v.y = qs[(seg * 4 + 1) * 65 + d];
            v.z = qs[(seg * 4 + 2) * 65 + d];
            v.w = qs[(seg * 4 + 3) * 65 + d];
            __builtin_nontemporal_store(v, (f32x4*)(qoB + (long)d * HW + seg * 4));
        }
    }
}

// ---------------------------------------------------------------------------
// Fill-style encodings writer: 524288 lanes x 16B per grid-stride iteration
// = one contiguous 8 MB window sweeping 268 MB linearly (fillBuffer's exact
// pattern). Skips each row's first f4 (the fidx stash) — vq_fix handles it.
// Stash read: 64 consecutive lanes span <=2 rows -> broadcast L2 load.
// ---------------------------------------------------------------------------
__global__ __launch_bounds__(256) void vq_enc(float* __restrict__ out)
{
    const long gid = (long)blockIdx.x * 256 + threadIdx.x;   // 0..524287
    float* encB = out + (long)OFF_ENC;
    #pragma unroll 1
    for (int it = 0; it < 32; it++) {
        long f4pos = gid + (long)it * 524288;    // 16 B units; 16.7M total
        long p     = f4pos >> 7;                 // row (128 f4 per 512-f row)
        int  k0    = ((int)f4pos & 127) << 2;    // float offset in row
        int  fd    = *(const int*)(encB + p * KCODES);   // stash
        if (k0 != 0) {
            f32x4 v;
            v.x = (k0     == fd) ? 1.0f : 0.0f;
            v.y = (k0 + 1 == fd) ? 1.0f : 0.0f;
            v.z = (k0 + 2 == fd) ? 1.0f : 0.0f;
            v.w = (k0 + 3 == fd) ? 1.0f : 0.0f;
            __builtin_nontemporal_store(v, (f32x4*)(encB + f4pos * 4));
        }
    }
}

// ---------------------------------------------------------------------------
// Fix pass: rewrite each enc row's first f4 (reads the stash it overwrites).
// ---------------------------------------------------------------------------
__global__ __launch_bounds__(256) void vq_fix(float* __restrict__ out)
{
    int n = blockIdx.x * 256 + threadIdx.x;      // 0..131071
    float* row = out + (long)OFF_ENC + (long)n * KCODES;
    int fd = *(const int*)row;
    f32x4 v;
    v.x = (0 == fd) ? 1.0f : 0.0f;
    v.y = (1 == fd) ? 1.0f : 0.0f;
    v.z = (2 == fd) ? 1.0f : 0.0f;
    v.w = (3 == fd) ? 1.0f : 0.0f;
    __builtin_nontemporal_store(v, (f32x4*)row);
}

// ---------------------------------------------------------------------------
// Finalize: loss scalar + perplexity (fp64)
// ---------------------------------------------------------------------------
__global__ void vq_finalize(const unsigned* __restrict__ hist,
                            const float* __restrict__ bloss,
                            float* __restrict__ out)
{
    __shared__ double sl[512];
    __shared__ double sh[512];
    int tid = threadIdx.x;   // 512

    double l = (double)bloss[tid] + (double)bloss[tid + 512]
             + (double)bloss[tid + 1024] + (double)bloss[tid + 1536];

    unsigned c = hist[tid];
    double p = (double)c * (1.0 / 131072.0);
    double h = p * log(p + 1e-10);

    sl[tid] = l;
    sh[tid] = h;
    __syncthreads();
    for (int s = 256; s > 0; s >>= 1) {
        if (tid < s) { sl[tid] += sl[tid + s]; sh[tid] += sh[tid + s]; }
        __syncthreads();
    }
    if (tid == 0) {
        out[OFF_LOSS] = (float)(0.25 * sl[0] / 8388608.0);
        out[OFF_PERP] = (float)exp(-sh[0]);
    }
}

// ---------------------------------------------------------------------------
extern "C" void kernel_launch(void* const* d_in, const int* in_sizes, int n_in,
                              void* d_out, int out_size, void* d_ws, size_t ws_size,
                              hipStream_t stream)
{
    const float* in  = (const float*)d_in[0];   // inputs  [32,64,64,64] f32
    const float* emb = (const float*)d_in[1];   // codebook [512,64] f32
    float* out = (float*)d_out;
    char*  ws  = (char*)d_ws;

    unsigned*       hist  = (unsigned*)      (ws + WS_HIST);
    float*          bloss = (float*)         (ws + WS_BLOSS);
    float*          nrm   = (float*)         (ws + WS_NRM);
    unsigned short* eh    = (unsigned short*)(ws + WS_EH);
    unsigned short* el    = (unsigned short*)(ws + WS_EL);

    vq_prep<<<KCODES, 64, 0, stream>>>(emb, eh, el, nrm, hist);
    vq_scan<<<2048, 64, 0, stream>>>(in, emb, eh, el, nrm, hist, bloss, out);
    vq_enc<<<2048, 256, 0, stream>>>(out);
    vq_fix<<<512, 256, 0, stream>>>(out);
    vq_finalize<<<1, 512, 0, stream>>>(hist, bloss, out);
}

// Round 14
// 439.285 us; speedup vs baseline: 1.2222x; 1.1871x over previous
//
#include <hip/hip_runtime.h>
#include <math.h>

// Problem constants
#define NPTS   131072          // 32*64*64 points
#define DIMS   64              // embedding dim / channels
#define KCODES 512             // codebook size
#define HW     4096            // 64*64 spatial

// d_out flat offsets (floats), reference tuple order:
// (loss, quantized_out[NCHW], perplexity, encodings, quantized_flat)
#define OFF_LOSS 0
#define OFF_QOUT 1
#define OFF_PERP 8388609
#define OFF_ENC  8388610
#define OFF_QF   75497474   // 8388610 + 67108864

// d_ws byte offsets
#define WS_HIST  0          // unsigned[512]  (zeroed by vq_prep)
#define WS_BLOSS 2048       // float[2048]
#define WS_NRM   10240      // float[512]
#define WS_EH    12288      // ushort[512*64] bf16 hi, MFMA-fragment order
#define WS_EL    77824      // ushort[512*64] bf16 lo, MFMA-fragment order

// split-bf16 distance error <~2.4e-4; pairwise comparison error <4.8e-4.
// margin 2e-3 still flags every possible argmin flip (4x cushion).
#define EPS_MARGIN 2e-3f

typedef __attribute__((ext_vector_type(8))) short short8;
typedef __attribute__((ext_vector_type(4))) float f32x4;

__device__ __forceinline__ unsigned short f2bf(float f) {
    unsigned u = __float_as_uint(f);
    unsigned r = (u + 0x7fffu + ((u >> 16) & 1u)) >> 16;   // RNE
    return (unsigned short)r;
}
__device__ __forceinline__ float bf2f(unsigned short h) {
    return __uint_as_float(((unsigned)h) << 16);
}

// ---------------------------------------------------------------------------
// Prep: split codebook into bf16 hi/lo in MFMA B-fragment order:
//   idx = ((t*2 + s)*64 + quad*16 + col)*8 + j,  k = t*16+col, d = s*32+quad*8+j
// so vq_fused's lane l loads short8 at [(t*2+s)*64 + l] -> fully coalesced.
// Also zeroes hist (replaces a separate memset dispatch).
// ---------------------------------------------------------------------------
__global__ void vq_prep(const float* __restrict__ emb,
                        unsigned short* __restrict__ ehF,
                        unsigned short* __restrict__ elF,
                        float* __restrict__ nrm,
                        unsigned* __restrict__ hist)
{
    int k = blockIdx.x;      // 512
    int d = threadIdx.x;     // 64
    float v = emb[k * DIMS + d];
    unsigned short h = f2bf(v);
    int t = k >> 4, col = k & 15;
    int s = d >> 5, quad = (d >> 3) & 3, j = d & 7;
    int idx = (((t * 2 + s) * 64) + quad * 16 + col) * 8 + j;
    ehF[idx] = h;
    elF[idx] = f2bf(v - bf2f(h));
    double sq = (double)v * (double)v;
    #pragma unroll
    for (int off = 32; off > 0; off >>= 1)
        sq += __shfl_down(sq, off, 64);
    if (d == 0) { nrm[k] = (float)sq; hist[k] = 0u; }
}

// ---------------------------------------------------------------------------
// ROUND-14: PLAIN STORES (one variable vs the proven R3 fused kernel).
// Closing the 13-round decomposition: kernel store BW is empirically capped
// at ~1.5-2.4 TB/s across ALL our variants (R9/R10/R11: 360-809 MB at
// 1.5-3.5 TB/s) while fillBufferAligned hits 6.3 TB/s in the same runs.
// 335.5 MB at 2.4 TB/s = ~140us -> the invariant ~200us chain IS the store
// drain; 9 scan restructurings were null because they never touched it.
// The one path difference: our stores were __builtin_nontemporal_store
// (L2-bypass streaming); fillBuffer uses plain stores that drain via L2 as
// full-line slice-ordered writebacks. This round: identical kernel, plain
// stores. NOTE: (256,2) is load-bearing (VGPR cap).
// ---------------------------------------------------------------------------
__global__ __launch_bounds__(256, 2) void vq_fused(
    const float*          __restrict__ in,    // NCHW [32][64][64][64]
    const float*          __restrict__ emb,   // [512][64] fp32 (recheck+gather)
    const unsigned short* __restrict__ eh,    // frag-order bf16 hi
    const unsigned short* __restrict__ el,    // frag-order bf16 lo
    const float*          __restrict__ nrm,   // [512] ||e||^2 fp32
    unsigned*             __restrict__ hist,  // [512]
    float*                __restrict__ bloss, // [2048]
    float*                __restrict__ out)
{
    __shared__ float xs[64 * 68];      // [p][d] x-tile, stride 68 (17 KB); reused as qs
    __shared__ float ns[512];
    __shared__ float psx[256];
    __shared__ float pdist[64];
    __shared__ int   fidx[64];
    __shared__ int   flagged[4][16];   // per-wave flag lists
    __shared__ int   nflagw[4];

    const int tid  = threadIdx.x;
    const int lane = tid & 63;
    const int dg   = tid >> 6;

    const int blk = blockIdx.x;          // 2048
    const int b   = blk >> 6;
    const int hw0 = (blk & 63) * 64;
    const long inBase = (long)b * (DIMS * HW) + hw0;

    // ---- stage x tile [p][d] ----
    {
        float ps = 0.f;
        #pragma unroll
        for (int i = 0; i < 16; i++) {
            int d = dg * 16 + i;
            float v = in[inBase + (long)d * HW + lane];
            xs[lane * 68 + d] = v;
            ps = fmaf(v, v, ps);
        }
        psx[tid] = ps;
    }
    ns[tid] = nrm[tid];
    ns[tid + 256] = nrm[tid + 256];
    if (tid < 4) nflagw[tid] = 0;
    __syncthreads();

    // ---- wave-level MFMA distance scan: 16 points x 512 codes per wave ----
    const int wid   = tid >> 6;
    const int l     = tid & 63;
    const int col   = l & 15;
    const int quad  = l >> 4;
    const int pbase = wid * 16;

    short8 ah[2], al[2];
    {
        const float* xrow = &xs[(pbase + col) * 68];
        #pragma unroll
        for (int s = 0; s < 2; s++) {
            int k0 = s * 32 + quad * 8;
            float xv[8];
            *(float4*)&xv[0] = *(const float4*)&xrow[k0];
            *(float4*)&xv[4] = *(const float4*)&xrow[k0 + 4];
            short8 h, lo;
            #pragma unroll
            for (int j = 0; j < 8; j++) {
                unsigned short hb = f2bf(xv[j]);
                h[j]  = (short)hb;
                lo[j] = (short)f2bf(xv[j] - bf2f(hb));
            }
            ah[s] = h; al[s] = lo;
        }
    }

    float b1[4], b2[4];
    int   i1[4];
    #pragma unroll
    for (int r = 0; r < 4; r++) { b1[r] = 1e30f; b2[r] = 1e30f; i1[r] = 0; }

    {
        const short8* bhF = (const short8*)eh;   // [(t*2+s)*64 + lane]
        const short8* blF = (const short8*)el;
        for (int t = 0; t < 32; t++) {
            short8 bh0 = bhF[(t * 2    ) * 64 + l];   // coalesced 1 KB/instr
            short8 bh1 = bhF[(t * 2 + 1) * 64 + l];
            short8 bl0 = blF[(t * 2    ) * 64 + l];
            short8 bl1 = blF[(t * 2 + 1) * 64 + l];

            f32x4 acc = {0.f, 0.f, 0.f, 0.f};
            acc = __builtin_amdgcn_mfma_f32_16x16x32_bf16(ah[0], bh0, acc, 0, 0, 0);
            acc = __builtin_amdgcn_mfma_f32_16x16x32_bf16(ah[1], bh1, acc, 0, 0, 0);
            acc = __builtin_amdgcn_mfma_f32_16x16x32_bf16(ah[0], bl0, acc, 0, 0, 0);
            acc = __builtin_amdgcn_mfma_f32_16x16x32_bf16(ah[1], bl1, acc, 0, 0, 0);
            acc = __builtin_amdgcn_mfma_f32_16x16x32_bf16(al[0], bh0, acc, 0, 0, 0);
            acc = __builtin_amdgcn_mfma_f32_16x16x32_bf16(al[1], bh1, acc, 0, 0, 0);

            int   k  = t * 16 + col;
            float nk = ns[k];
            #pragma unroll
            for (int r = 0; r < 4; r++) {
                float v = fmaf(-2.f, acc[r], nk);   // ||e||^2 - 2 x.e
                bool better = (v < b1[r]);
                b2[r] = better ? b1[r] : fminf(b2[r], v);
                i1[r] = better ? k : i1[r];
                b1[r] = better ? v : b1[r];
            }
        }
    }

    // ---- reduce over 16 code-columns ----
    #pragma unroll
    for (int r = 0; r < 4; r++) {
        float b1v = b1[r], b2v = b2[r];
        int   i1v = i1[r];
        #pragma unroll
        for (int m = 1; m < 16; m <<= 1) {
            float ob1 = __shfl_xor(b1v, m);
            int   oi1 = __shfl_xor(i1v, m);
            float ob2 = __shfl_xor(b2v, m);
            float loser = fmaxf(b1v, ob1);
            b2v = fminf(fminf(b2v, ob2), loser);
            if (ob1 < b1v || (ob1 == b1v && oi1 < i1v)) { b1v = ob1; i1v = oi1; }
        }
        if (col == 0) {
            int p = pbase + quad * 4 + r;    // D row = quad*4 + reg
            fidx[p] = i1v;
            float sx = psx[p] + psx[64 + p] + psx[128 + p] + psx[192 + p];
            pdist[p] = sx + b1v;
            if (b2v - b1v < EPS_MARGIN) {
                int s = atomicAdd(&nflagw[wid], 1);
                flagged[wid][s] = p;
            }
        }
    }
    // no barrier: each wave consumes only its own flags (LDS wave-coherent)

    // ---- wave-local fp64 re-scan for near-tie points (rare) ----
    {
        int nf = nflagw[wid];
        for (int f = 0; f < nf; f++) {
            int p = flagged[wid][f];
            double bd = 1e300;
            int    bk = 1 << 30;
            #pragma unroll 2
            for (int kk = 0; kk < 8; kk++) {
                int k = (kk << 6) + l;           // lane's codes: l, l+64, ...
                const float4* er = (const float4*)(emb + k * DIMS);
                double s = 0.0;
                #pragma unroll 4
                for (int i = 0; i < 16; i++) {
                    float4 e4 = er[i];
                    double d0 = (double)xs[p * 68 + i * 4    ] - (double)e4.x;
                    double d1 = (double)xs[p * 68 + i * 4 + 1] - (double)e4.y;
                    double d2 = (double)xs[p * 68 + i * 4 + 2] - (double)e4.z;
                    double d3 = (double)xs[p * 68 + i * 4 + 3] - (double)e4.w;
                    s = fma(d0, d0, s); s = fma(d1, d1, s);
                    s = fma(d2, d2, s); s = fma(d3, d3, s);
                }
                if (s < bd || (s == bd && k < bk)) { bd = s; bk = k; }
            }
            #pragma unroll
            for (int off = 32; off > 0; off >>= 1) {
                double ov = __shfl_down(bd, off);
                int    ok = __shfl_down(bk, off);
                if (ov < bd || (ov == bd && ok < bk)) { bd = ov; bk = ok; }
            }
            if (l == 0) {
                fidx[p]  = bk;
                pdist[p] = (float)bd;
            }
        }
    }
    __syncthreads();   // fidx/pdist final before hist + stores

    // ---- histogram + loss partial ----
    if (tid < 64) {
        atomicAdd(&hist[fidx[tid]], 1u);
        float lp = pdist[tid];
        #pragma unroll
        for (int off = 32; off > 0; off >>= 1)
            lp += __shfl_down(lp, off);
        if (tid == 0) bloss[blk] = lp;
    }
    __syncthreads();   // all xs reads done before qs overwrite

    // ---- stage chosen embedding rows into qs (aliases xs, stride 65) ----
    float* qs = xs;
    {
        int q = tid & 3, p = tid >> 2;
        int row = fidx[p];
        const float4* src = (const float4*)(emb + row * DIMS + q * 16);
        #pragma unroll
        for (int i = 0; i < 4; i++) {
            float4 v = src[i];
            int base = p * 65 + q * 16 + i * 4;
            qs[base] = v.x; qs[base + 1] = v.y; qs[base + 2] = v.z; qs[base + 3] = v.w;
        }
    }

    const int n0 = b * HW + hw0;

    // ---- encodings: full one-hot rows (PLAIN stores, via L2) ----
    {
        float* encB = out + (long)OFF_ENC + (long)n0 * KCODES;
        #pragma unroll 4
        for (int i = 0; i < 32; i++) {
            int f  = i * 1024 + tid * 4;
            int p  = f >> 9;
            int k0 = f & 511;
            int fd = fidx[p];
            f32x4 v;
            v.x = (k0     == fd) ? 1.0f : 0.0f;
            v.y = (k0 + 1 == fd) ? 1.0f : 0.0f;
            v.z = (k0 + 2 == fd) ? 1.0f : 0.0f;
            v.w = (k0 + 3 == fd) ? 1.0f : 0.0f;
            *(f32x4*)(encB + f) = v;
        }
    }
    __syncthreads();   // qs staged before transpose reads

    // ---- quantized_flat [n][64] (PLAIN stores) ----
    {
        float* qfB = out + (long)OFF_QF + (long)n0 * DIMS;
        #pragma unroll
        for (int i = 0; i < 4; i++) {
            int f = i * 1024 + tid * 4;
            int p = f >> 6;
            int d = f & 63;
            f32x4 v;
            v.x = qs[p * 65 + d];     v.y = qs[p * 65 + d + 1];
            v.z = qs[p * 65 + d + 2]; v.w = qs[p * 65 + d + 3];
            *(f32x4*)(qfB + f) = v;
        }
    }

    // ---- quantized_out NCHW: 1024 float4 per block (PLAIN stores) ----
    {
        float* qoB = out + (long)OFF_QOUT + (long)b * (DIMS * HW) + hw0;
        #pragma unroll
        for (int i = 0; i < 4; i++) {
            int f4  = i * 256 + tid;
            int d   = f4 >> 4;        // row 0..63
            int seg = f4 & 15;        // float4 segment within row
            f32x4 v;
            v.x = qs[(seg * 4    ) * 65 + d];
            v.y = qs[(seg * 4 + 1) * 65 + d];
            v.z = qs[(seg * 4 + 2) * 65 + d];
            v.w = qs[(seg * 4 + 3) * 65 + d];
            *(f32x4*)(qoB + (long)d * HW + seg * 4) = v;
        }
    }
}

// ---------------------------------------------------------------------------
// Finalize: loss scalar + perplexity (fp64)
// ---------------------------------------------------------------------------
__global__ void vq_finalize(const unsigned* __restrict__ hist,
                            const float* __restrict__ bloss,
                            float* __restrict__ out)
{
    __shared__ double sl[512];
    __shared__ double sh[512];
    int tid = threadIdx.x;   // 512

    double l = (double)bloss[tid] + (double)bloss[tid + 512]
             + (double)bloss[tid + 1024] + (double)bloss[tid + 1536];

    unsigned c = hist[tid];
    double p = (double)c * (1.0 / 131072.0);
    double h = p * log(p + 1e-10);

    sl[tid] = l;
    sh[tid] = h;
    __syncthreads();
    for (int s = 256; s > 0; s >>= 1) {
        if (tid < s) { sl[tid] += sl[tid + s]; sh[tid] += sh[tid + s]; }
        __syncthreads();
    }
    if (tid == 0) {
        out[OFF_LOSS] = (float)(0.25 * sl[0] / 8388608.0);
        out[OFF_PERP] = (float)exp(-sh[0]);
    }
}

// ---------------------------------------------------------------------------
extern "C" void kernel_launch(void* const* d_in, const int* in_sizes, int n_in,
                              void* d_out, int out_size, void* d_ws, size_t ws_size,
                              hipStream_t stream)
{
    const float* in  = (const float*)d_in[0];   // inputs  [32,64,64,64] f32
    const float* emb = (const float*)d_in[1];   // codebook [512,64] f32
    float* out = (float*)d_out;
    char*  ws  = (char*)d_ws;

    unsigned*       hist  = (unsigned*)      (ws + WS_HIST);
    float*          bloss = (float*)         (ws + WS_BLOSS);
    float*          nrm   = (float*)         (ws + WS_NRM);
    unsigned short* eh    = (unsigned short*)(ws + WS_EH);
    unsigned short* el    = (unsigned short*)(ws + WS_EL);

    vq_prep<<<KCODES, 64, 0, stream>>>(emb, eh, el, nrm, hist);
    vq_fused<<<2048, 256, 0, stream>>>(in, emb, eh, el, nrm, hist, bloss, out);
    vq_finalize<<<1, 512, 0, stream>>>(hist, bloss, out);
}

// Round 15
// 416.820 us; speedup vs baseline: 1.2880x; 1.0539x over previous
//
#include <hip/hip_runtime.h>
#include <math.h>

// Problem constants
#define NPTS   131072          // 32*64*64 points
#define DIMS   64              // embedding dim / channels
#define KCODES 512             // codebook size
#define HW     4096            // 64*64 spatial

// d_out flat offsets (floats), reference tuple order:
// (loss, quantized_out[NCHW], perplexity, encodings, quantized_flat)
#define OFF_LOSS 0
#define OFF_QOUT 1
#define OFF_PERP 8388609
#define OFF_ENC  8388610
#define OFF_QF   75497474   // 8388610 + 67108864

// split-bf16 distance error <~2.4e-4; pairwise comparison error <4.8e-4.
// margin 2e-3 still flags every possible argmin flip (4x cushion).
#define EPS_MARGIN 2e-3f

typedef __attribute__((ext_vector_type(8))) short short8;
typedef __attribute__((ext_vector_type(4))) float f32x4;

__device__ __forceinline__ unsigned short f2bf(float f) {
    unsigned u = __float_as_uint(f);
    unsigned r = (u + 0x7fffu + ((u >> 16) & 1u)) >> 16;   // RNE
    return (unsigned short)r;
}
__device__ __forceinline__ float bf2f(unsigned short h) {
    return __uint_as_float(((unsigned)h) << 16);
}

// ---------------------------------------------------------------------------
// Prep: split codebook into bf16 hi/lo in MFMA B-fragment order (see R3).
// Zeroes the (possibly line-spread) histogram.
// ---------------------------------------------------------------------------
__global__ void vq_prep(const float* __restrict__ emb,
                        unsigned short* __restrict__ ehF,
                        unsigned short* __restrict__ elF,
                        float* __restrict__ nrm,
                        unsigned* __restrict__ hist,
                        int hmask)
{
    int k = blockIdx.x;      // 512
    int d = threadIdx.x;     // 64
    float v = emb[k * DIMS + d];
    unsigned short h = f2bf(v);
    int t = k >> 4, col = k & 15;
    int s = d >> 5, quad = (d >> 3) & 3, j = d & 7;
    int idx = (((t * 2 + s) * 64) + quad * 16 + col) * 8 + j;
    ehF[idx] = h;
    elF[idx] = f2bf(v - bf2f(h));
    double sq = (double)v * (double)v;
    #pragma unroll
    for (int off = 32; off > 0; off >>= 1)
        sq += __shfl_down(sq, off, 64);
    if (d == 0) nrm[k] = (float)sq;
    if (d <= hmask) hist[k * (hmask + 1) + d] = 0u;
}

// ---------------------------------------------------------------------------
// ROUND-15: HISTOGRAM LINE-SPREAD. The one operation byte-identical across
// all 14 rounds is 131,072 device-scope atomicAdds onto a 512-counter
// (32-cache-line) histogram. Mechanism: cross-XCD atomics to contended lines
// serialize at the fabric line-ownership rate (~0.5/cyc chip-wide ~= the
// invariant 140-180us); waves pile up at endpgm vmcnt drain -> all pipes
// idle, content/occupancy-invariant, PMC-invisible. This round (one
// variable vs the proven R3 kernel): spread each code across 16 lines,
// hist[k*16 + (blk&15)] (8192 counters, 512 lines; per-line contention
// 4096 -> 256); finalize sums the 16 sub-counters. Host falls back to
// spread=1 (identical to R3) if ws_size is too small.
// NOTE: (256,2) is load-bearing (VGPR cap). NT stores (R14: plain is worse).
// ---------------------------------------------------------------------------
__global__ __launch_bounds__(256, 2) void vq_fused(
    const float*          __restrict__ in,    // NCHW [32][64][64][64]
    const float*          __restrict__ emb,   // [512][64] fp32 (recheck+gather)
    const unsigned short* __restrict__ eh,    // frag-order bf16 hi
    const unsigned short* __restrict__ el,    // frag-order bf16 lo
    const float*          __restrict__ nrm,   // [512] ||e||^2 fp32
    unsigned*             __restrict__ hist,  // [512*(hmask+1)]
    float*                __restrict__ bloss, // [2048]
    float*                __restrict__ out,
    int hmask)
{
    __shared__ float xs[64 * 68];      // [p][d] x-tile, stride 68 (17 KB); reused as qs
    __shared__ float ns[512];
    __shared__ float psx[256];
    __shared__ float pdist[64];
    __shared__ int   fidx[64];
    __shared__ int   flagged[4][16];   // per-wave flag lists
    __shared__ int   nflagw[4];

    const int tid  = threadIdx.x;
    const int lane = tid & 63;
    const int dg   = tid >> 6;

    const int blk = blockIdx.x;          // 2048
    const int b   = blk >> 6;
    const int hw0 = (blk & 63) * 64;
    const long inBase = (long)b * (DIMS * HW) + hw0;

    // ---- stage x tile [p][d] ----
    {
        float ps = 0.f;
        #pragma unroll
        for (int i = 0; i < 16; i++) {
            int d = dg * 16 + i;
            float v = in[inBase + (long)d * HW + lane];
            xs[lane * 68 + d] = v;
            ps = fmaf(v, v, ps);
        }
        psx[tid] = ps;
    }
    ns[tid] = nrm[tid];
    ns[tid + 256] = nrm[tid + 256];
    if (tid < 4) nflagw[tid] = 0;
    __syncthreads();

    // ---- wave-level MFMA distance scan: 16 points x 512 codes per wave ----
    const int wid   = tid >> 6;
    const int l     = tid & 63;
    const int col   = l & 15;
    const int quad  = l >> 4;
    const int pbase = wid * 16;

    short8 ah[2], al[2];
    {
        const float* xrow = &xs[(pbase + col) * 68];
        #pragma unroll
        for (int s = 0; s < 2; s++) {
            int k0 = s * 32 + quad * 8;
            float xv[8];
            *(float4*)&xv[0] = *(const float4*)&xrow[k0];
            *(float4*)&xv[4] = *(const float4*)&xrow[k0 + 4];
            short8 h, lo;
            #pragma unroll
            for (int j = 0; j < 8; j++) {
                unsigned short hb = f2bf(xv[j]);
                h[j]  = (short)hb;
                lo[j] = (short)f2bf(xv[j] - bf2f(hb));
            }
            ah[s] = h; al[s] = lo;
        }
    }

    float b1[4], b2[4];
    int   i1[4];
    #pragma unroll
    for (int r = 0; r < 4; r++) { b1[r] = 1e30f; b2[r] = 1e30f; i1[r] = 0; }

    {
        const short8* bhF = (const short8*)eh;   // [(t*2+s)*64 + lane]
        const short8* blF = (const short8*)el;
        for (int t = 0; t < 32; t++) {
            short8 bh0 = bhF[(t * 2    ) * 64 + l];   // coalesced 1 KB/instr
            short8 bh1 = bhF[(t * 2 + 1) * 64 + l];
            short8 bl0 = blF[(t * 2    ) * 64 + l];
            short8 bl1 = blF[(t * 2 + 1) * 64 + l];

            f32x4 acc = {0.f, 0.f, 0.f, 0.f};
            acc = __builtin_amdgcn_mfma_f32_16x16x32_bf16(ah[0], bh0, acc, 0, 0, 0);
            acc = __builtin_amdgcn_mfma_f32_16x16x32_bf16(ah[1], bh1, acc, 0, 0, 0);
            acc = __builtin_amdgcn_mfma_f32_16x16x32_bf16(ah[0], bl0, acc, 0, 0, 0);
            acc = __builtin_amdgcn_mfma_f32_16x16x32_bf16(ah[1], bl1, acc, 0, 0, 0);
            acc = __builtin_amdgcn_mfma_f32_16x16x32_bf16(al[0], bh0, acc, 0, 0, 0);
            acc = __builtin_amdgcn_mfma_f32_16x16x32_bf16(al[1], bh1, acc, 0, 0, 0);

            int   k  = t * 16 + col;
            float nk = ns[k];
            #pragma unroll
            for (int r = 0; r < 4; r++) {
                float v = fmaf(-2.f, acc[r], nk);   // ||e||^2 - 2 x.e
                bool better = (v < b1[r]);
                b2[r] = better ? b1[r] : fminf(b2[r], v);
                i1[r] = better ? k : i1[r];
                b1[r] = better ? v : b1[r];
            }
        }
    }

    // ---- reduce over 16 code-columns ----
    #pragma unroll
    for (int r = 0; r < 4; r++) {
        float b1v = b1[r], b2v = b2[r];
        int   i1v = i1[r];
        #pragma unroll
        for (int m = 1; m < 16; m <<= 1) {
            float ob1 = __shfl_xor(b1v, m);
            int   oi1 = __shfl_xor(i1v, m);
            float ob2 = __shfl_xor(b2v, m);
            float loser = fmaxf(b1v, ob1);
            b2v = fminf(fminf(b2v, ob2), loser);
            if (ob1 < b1v || (ob1 == b1v && oi1 < i1v)) { b1v = ob1; i1v = oi1; }
        }
        if (col == 0) {
            int p = pbase + quad * 4 + r;    // D row = quad*4 + reg
            fidx[p] = i1v;
            float sx = psx[p] + psx[64 + p] + psx[128 + p] + psx[192 + p];
            pdist[p] = sx + b1v;
            if (b2v - b1v < EPS_MARGIN) {
                int s = atomicAdd(&nflagw[wid], 1);
                flagged[wid][s] = p;
            }
        }
    }
    // no barrier: each wave consumes only its own flags (LDS wave-coherent)

    // ---- wave-local fp64 re-scan for near-tie points (rare) ----
    {
        int nf = nflagw[wid];
        for (int f = 0; f < nf; f++) {
            int p = flagged[wid][f];
            double bd = 1e300;
            int    bk = 1 << 30;
            #pragma unroll 2
            for (int kk = 0; kk < 8; kk++) {
                int k = (kk << 6) + l;           // lane's codes: l, l+64, ...
                const float4* er = (const float4*)(emb + k * DIMS);
                double s = 0.0;
                #pragma unroll 4
                for (int i = 0; i < 16; i++) {
                    float4 e4 = er[i];
                    double d0 = (double)xs[p * 68 + i * 4    ] - (double)e4.x;
                    double d1 = (double)xs[p * 68 + i * 4 + 1] - (double)e4.y;
                    double d2 = (double)xs[p * 68 + i * 4 + 2] - (double)e4.z;
                    double d3 = (double)xs[p * 68 + i * 4 + 3] - (double)e4.w;
                    s = fma(d0, d0, s); s = fma(d1, d1, s);
                    s = fma(d2, d2, s); s = fma(d3, d3, s);
                }
                if (s < bd || (s == bd && k < bk)) { bd = s; bk = k; }
            }
            #pragma unroll
            for (int off = 32; off > 0; off >>= 1) {
                double ov = __shfl_down(bd, off);
                int    ok = __shfl_down(bk, off);
                if (ov < bd || (ov == bd && ok < bk)) { bd = ov; bk = ok; }
            }
            if (l == 0) {
                fidx[p]  = bk;
                pdist[p] = (float)bd;
            }
        }
    }
    __syncthreads();   // fidx/pdist final before hist + stores

    // ---- histogram (line-spread) + loss partial ----
    if (tid < 64) {
        atomicAdd(&hist[fidx[tid] * (hmask + 1) + (blk & hmask)], 1u);
        float lp = pdist[tid];
        #pragma unroll
        for (int off = 32; off > 0; off >>= 1)
            lp += __shfl_down(lp, off);
        if (tid == 0) bloss[blk] = lp;
    }
    __syncthreads();   // all xs reads done before qs overwrite

    // ---- stage chosen embedding rows into qs (aliases xs, stride 65) ----
    float* qs = xs;
    {
        int q = tid & 3, p = tid >> 2;
        int row = fidx[p];
        const float4* src = (const float4*)(emb + row * DIMS + q * 16);
        #pragma unroll
        for (int i = 0; i < 4; i++) {
            float4 v = src[i];
            int base = p * 65 + q * 16 + i * 4;
            qs[base] = v.x; qs[base + 1] = v.y; qs[base + 2] = v.z; qs[base + 3] = v.w;
        }
    }

    const int n0 = b * HW + hw0;

    // ---- encodings: full one-hot rows (needs only fidx; overlaps staging) ----
    {
        float* encB = out + (long)OFF_ENC + (long)n0 * KCODES;
        #pragma unroll 4
        for (int i = 0; i < 32; i++) {
            int f  = i * 1024 + tid * 4;
            int p  = f >> 9;
            int k0 = f & 511;
            int fd = fidx[p];
            f32x4 v;
            v.x = (k0     == fd) ? 1.0f : 0.0f;
            v.y = (k0 + 1 == fd) ? 1.0f : 0.0f;
            v.z = (k0 + 2 == fd) ? 1.0f : 0.0f;
            v.w = (k0 + 3 == fd) ? 1.0f : 0.0f;
            __builtin_nontemporal_store(v, (f32x4*)(encB + f));
        }
    }
    __syncthreads();   // qs staged before transpose reads

    // ---- quantized_flat [n][64] ----
    {
        float* qfB = out + (long)OFF_QF + (long)n0 * DIMS;
        #pragma unroll
        for (int i = 0; i < 4; i++) {
            int f = i * 1024 + tid * 4;
            int p = f >> 6;
            int d = f & 63;
            f32x4 v;
            v.x = qs[p * 65 + d];     v.y = qs[p * 65 + d + 1];
            v.z = qs[p * 65 + d + 2]; v.w = qs[p * 65 + d + 3];
            __builtin_nontemporal_store(v, (f32x4*)(qfB + f));
        }
    }

    // ---- quantized_out NCHW: 1024 float4 per block (4/thread) ----
    {
        float* qoB = out + (long)OFF_QOUT + (long)b * (DIMS * HW) + hw0;
        #pragma unroll
        for (int i = 0; i < 4; i++) {
            int f4  = i * 256 + tid;
            int d   = f4 >> 4;        // row 0..63
            int seg = f4 & 15;        // float4 segment within row
            f32x4 v;
            v.x = qs[(seg * 4    ) * 65 + d];
            v.y = qs[(seg * 4 + 1) * 65 + d];
            v.z = qs[(seg * 4 + 2) * 65 + d];
            v.w = qs[(seg * 4 + 3) * 65 + d];
            __builtin_nontemporal_store(v, (f32x4*)(qoB + (long)d * HW + seg * 4));
        }
    }
}

// ---------------------------------------------------------------------------
// Finalize: loss scalar + perplexity (fp64); sums the spread sub-counters.
// ---------------------------------------------------------------------------
__global__ void vq_finalize(const unsigned* __restrict__ hist,
                            const float* __restrict__ bloss,
                            float* __restrict__ out,
                            int hmask)
{
    __shared__ double sl[512];
    __shared__ double sh[512];
    int tid = threadIdx.x;   // 512

    double l = (double)bloss[tid] + (double)bloss[tid + 512]
             + (double)bloss[tid + 1024] + (double)bloss[tid + 1536];

    unsigned c = 0;
    for (int s = 0; s <= hmask; s++)
        c += hist[tid * (hmask + 1) + s];
    double p = (double)c * (1.0 / 131072.0);
    double h = p * log(p + 1e-10);

    sl[tid] = l;
    sh[tid] = h;
    __syncthreads();
    for (int s = 256; s > 0; s >>= 1) {
        if (tid < s) { sl[tid] += sl[tid + s]; sh[tid] += sh[tid + s]; }
        __syncthreads();
    }
    if (tid == 0) {
        out[OFF_LOSS] = (float)(0.25 * sl[0] / 8388608.0);
        out[OFF_PERP] = (float)exp(-sh[0]);
    }
}

// ---------------------------------------------------------------------------
extern "C" void kernel_launch(void* const* d_in, const int* in_sizes, int n_in,
                              void* d_out, int out_size, void* d_ws, size_t ws_size,
                              hipStream_t stream)
{
    const float* in  = (const float*)d_in[0];   // inputs  [32,64,64,64] f32
    const float* emb = (const float*)d_in[1];   // codebook [512,64] f32
    float* out = (float*)d_out;
    char*  ws  = (char*)d_ws;

    // ws layout (spread-16): hist 32KB | bloss 8KB | nrm 2KB | eh 64KB | el 64KB
    // fallback (spread-1):   hist 2KB  | bloss 8KB | nrm 2KB | eh 64KB | el 64KB
    const int spread = (ws_size >= 174080) ? 16 : 1;
    const int hmask  = spread - 1;
    size_t off_hist = 0;
    size_t off_bloss = (size_t)512 * spread * 4;
    size_t off_nrm   = off_bloss + 8192;
    size_t off_eh    = off_nrm + 2048;
    size_t off_el    = off_eh + 65536;

    unsigned*       hist  = (unsigned*)      (ws + off_hist);
    float*          bloss = (float*)         (ws + off_bloss);
    float*          nrm   = (float*)         (ws + off_nrm);
    unsigned short* eh    = (unsigned short*)(ws + off_eh);
    unsigned short* el    = (unsigned short*)(ws + off_el);

    vq_prep<<<KCODES, 64, 0, stream>>>(emb, eh, el, nrm, hist, hmask);
    vq_fused<<<2048, 256, 0, stream>>>(in, emb, eh, el, nrm, hist, bloss, out, hmask);
    vq_finalize<<<1, 512, 0, stream>>>(hist, bloss, out, hmask);
}